// Round 1
// baseline (444.265 us; speedup 1.0000x reference)
//
#include <hip/hip_runtime.h>
#include <hip/hip_bf16.h>

// RoIAlign (avg, aligned=True) — faithful port of torchvision roi_align.
// Problem constants from the reference:
//   input: (4, 256, 200, 200) fp32, rois: (1024, 5) fp32
//   pooled 7x7, sampling_ratio=2, spatial_scale=0.25
// Output: (1024, 256, 7, 7) fp32 = 12,845,056 elements.

#define POOLED_H 7
#define POOLED_W 7
#define SR 2
#define N_IMG 4
#define CCH 256
#define FH 200
#define FW 200
#define SPATIAL_SCALE 0.25f

__global__ __launch_bounds__(256) void roi_align_kernel(
    const float* __restrict__ feat,   // (N_IMG, C, H, W)
    const float* __restrict__ rois,   // (N_ROIS, 5)
    float* __restrict__ out,          // (N_ROIS, C, PH, PW)
    int total)
{
    int idx = blockIdx.x * blockDim.x + threadIdx.x;
    if (idx >= total) return;

    int pw = idx % POOLED_W;
    int ph = (idx / POOLED_W) % POOLED_H;
    int c  = (idx / (POOLED_W * POOLED_H)) % CCH;
    int n  = idx / (POOLED_W * POOLED_H * CCH);

    const float* roi = rois + n * 5;
    int   b  = (int)roi[0];
    float x1 = roi[1] * SPATIAL_SCALE - 0.5f;
    float y1 = roi[2] * SPATIAL_SCALE - 0.5f;
    float x2 = roi[3] * SPATIAL_SCALE - 0.5f;
    float y2 = roi[4] * SPATIAL_SCALE - 0.5f;

    float bin_h = (y2 - y1) * (1.0f / POOLED_H);
    float bin_w = (x2 - x1) * (1.0f / POOLED_W);

    const float* plane = feat + ((size_t)b * CCH + c) * (FH * FW);

    float acc = 0.0f;
    #pragma unroll
    for (int iy = 0; iy < SR; ++iy) {
        float y = y1 + ((float)ph + ((float)iy + 0.5f) * (1.0f / SR)) * bin_h;
        if (y < -1.0f || y > (float)FH) continue;
        float yc  = fminf(fmaxf(y, 0.0f), (float)(FH - 1));
        int   y0  = (int)yc;                       // yc >= 0 -> trunc == floor
        int   y1i = min(y0 + 1, FH - 1);
        float ly  = yc - (float)y0;
        float hy  = 1.0f - ly;

        #pragma unroll
        for (int ix = 0; ix < SR; ++ix) {
            float x = x1 + ((float)pw + ((float)ix + 0.5f) * (1.0f / SR)) * bin_w;
            if (x < -1.0f || x > (float)FW) continue;
            float xc  = fminf(fmaxf(x, 0.0f), (float)(FW - 1));
            int   x0  = (int)xc;
            int   x1i = min(x0 + 1, FW - 1);
            float lx  = xc - (float)x0;
            float hx  = 1.0f - lx;

            float v00 = plane[y0  * FW + x0 ];
            float v01 = plane[y0  * FW + x1i];
            float v10 = plane[y1i * FW + x0 ];
            float v11 = plane[y1i * FW + x1i];

            acc += hy * hx * v00 + hy * lx * v01
                 + ly * hx * v10 + ly * lx * v11;
        }
    }

    out[idx] = acc * (1.0f / (SR * SR));
}

extern "C" void kernel_launch(void* const* d_in, const int* in_sizes, int n_in,
                              void* d_out, int out_size, void* d_ws, size_t ws_size,
                              hipStream_t stream)
{
    const float* feat = (const float*)d_in[0];
    const float* rois = (const float*)d_in[1];
    float* out = (float*)d_out;

    int total = out_size;  // 1024 * 256 * 7 * 7
    int block = 256;
    int grid = (total + block - 1) / block;
    roi_align_kernel<<<grid, block, 0, stream>>>(feat, rois, out, total);
}

// Round 2
// 361.690 us; speedup vs baseline: 1.2283x; 1.2283x over previous
//
#include <hip/hip_runtime.h>
#include <hip/hip_bf16.h>

// RoIAlign (avg, aligned=True).
//   input: (4, 256, 200, 200) fp32, rois: (1024, 5) fp32
//   pooled 7x7, sampling_ratio=2, spatial_scale=0.25
//   out: (1024, 256, 7, 7) fp32 = 12,845,056 elements.
//
// R1 changes vs baseline:
//  - index order: channel OUTERMOST (all ROIs of a channel run temporally
//    adjacent; per-channel working set = 4 planes = 640 KB, fits L2)
//  - XCD swizzle: vid = (bid%8)*(nb/8)+bid/8 pins each channel's workgroups
//    to one XCD so its L2 keeps the planes resident (locality heuristic only)
//  - paired x loads: (v00,v01) and (v10,v11) fetched as one 8B load each
//    (16 -> 8 gather instructions per output)

#define SR 2
#define CCH 256
#define FH 200
#define FW 200
#define N_ROIS 1024
#define SPATIAL_SCALE 0.25f

__global__ __launch_bounds__(256) void roi_align_kernel(
    const float* __restrict__ feat,   // (N_IMG, C, H, W)
    const float* __restrict__ rois,   // (N_ROIS, 5)
    float* __restrict__ out,          // (N_ROIS, C, 7, 7)
    int total)
{
    // XCD-aware swizzle: consecutive virtual ids land on the same XCD
    // (assuming round-robin wg->XCD dispatch; perf heuristic only).
    int nb  = gridDim.x;                       // 50176, divisible by 8
    int vid = (blockIdx.x & 7) * (nb >> 3) + (blockIdx.x >> 3);
    int idx = vid * 256 + threadIdx.x;
    if (idx >= total) return;

    // channel-outermost decomposition
    int pw = idx % 7;
    int ph = (idx / 7) % 7;
    int n  = (idx / 49) & (N_ROIS - 1);
    int c  = idx / (49 * N_ROIS);

    const float* roi = rois + n * 5;
    int   b  = (int)roi[0];
    float x1 = roi[1] * SPATIAL_SCALE - 0.5f;
    float y1 = roi[2] * SPATIAL_SCALE - 0.5f;
    float x2 = roi[3] * SPATIAL_SCALE - 0.5f;
    float y2 = roi[4] * SPATIAL_SCALE - 0.5f;

    float bin_h = (y2 - y1) * (1.0f / 7.0f);
    float bin_w = (x2 - x1) * (1.0f / 7.0f);

    const float* plane = feat + ((size_t)b * CCH + c) * (FH * FW);

    // Precompute x-sample state once (shared by both iy samples).
    float lxv[SR], hxv[SR];
    int   xbv[SR];
    bool  xok[SR], xsh[SR];
    #pragma unroll
    for (int ix = 0; ix < SR; ++ix) {
        float x = x1 + ((float)pw + ((float)ix + 0.5f) * 0.5f) * bin_w;
        xok[ix] = (x >= -1.0f) && (x <= (float)FW);
        float xc = fminf(fmaxf(x, 0.0f), (float)(FW - 1));
        int x0 = (int)xc;                 // xc >= 0 -> trunc == floor
        int xb = min(x0, FW - 2);         // pair base; avoids OOB at x0==199
        xbv[ix] = xb;
        xsh[ix] = (x0 > xb);              // x0==199 -> lx==0, pair shifted
        float lx = xc - (float)x0;
        lxv[ix] = lx;
        hxv[ix] = 1.0f - lx;
    }

    float acc = 0.0f;
    #pragma unroll
    for (int iy = 0; iy < SR; ++iy) {
        float y = y1 + ((float)ph + ((float)iy + 0.5f) * 0.5f) * bin_h;
        if (y < -1.0f || y > (float)FH) continue;
        float yc  = fminf(fmaxf(y, 0.0f), (float)(FH - 1));
        int   y0  = (int)yc;
        int   y1i = min(y0 + 1, FH - 1);
        float ly  = yc - (float)y0;
        float hy  = 1.0f - ly;

        const float* r0 = plane + y0  * FW;
        const float* r1 = plane + y1i * FW;

        #pragma unroll
        for (int ix = 0; ix < SR; ++ix) {
            if (!xok[ix]) continue;
            float p0[2], p1[2];
            __builtin_memcpy(p0, r0 + xbv[ix], 8);   // (v00, v01) pair
            __builtin_memcpy(p1, r1 + xbv[ix], 8);   // (v10, v11) pair
            float v00 = xsh[ix] ? p0[1] : p0[0];
            float v01 = p0[1];
            float v10 = xsh[ix] ? p1[1] : p1[0];
            float v11 = p1[1];
            acc += hy * (hxv[ix] * v00 + lxv[ix] * v01)
                 + ly * (hxv[ix] * v10 + lxv[ix] * v11);
        }
    }

    out[idx >= 0 ? ((size_t)n * CCH + c) * 49 + ph * 7 + pw : 0] = acc * 0.25f;
}

extern "C" void kernel_launch(void* const* d_in, const int* in_sizes, int n_in,
                              void* d_out, int out_size, void* d_ws, size_t ws_size,
                              hipStream_t stream)
{
    const float* feat = (const float*)d_in[0];
    const float* rois = (const float*)d_in[1];
    float* out = (float*)d_out;

    int total = out_size;                 // 12,845,056
    int block = 256;
    int grid = (total + block - 1) / block;   // 50176, divisible by 8
    roi_align_kernel<<<grid, block, 0, stream>>>(feat, rois, out, total);
}

// Round 3
// 297.230 us; speedup vs baseline: 1.4947x; 1.2169x over previous
//
#include <hip/hip_runtime.h>
#include <hip/hip_bf16.h>

// RoIAlign (avg, aligned=True).
//   input: (4, 256, 200, 200) fp32, rois: (1024, 5) fp32
//   pooled 7x7, sampling_ratio=2, spatial_scale=0.25
//   out: (1024, 256, 7, 7) fp32
//
// R2: two-pass. Pass 1 repacks NCHW fp32 -> grouped-32 bf16 layout
// ws[b][g][y][x][32c] so one pixel's channel-group = one 64B cache line.
// Pass 2 gathers bilinear corners with fully-utilized 16B loads
// (wave = 16 bins x 4 channel-slices covering whole lines).

#define CCH 256
#define FH 200
#define FW 200
#define N_ROIS 1024
#define PP 49          // 7*7 bins
#define NG 8           // channel groups (256/32)
#define GSZ 32         // channels per group
#define PLANE (FH*FW)

// ---------- pass 1: NCHW fp32 -> grouped bf16 ----------
// item = (b*8+g, pixel); reads 32 coalesced streams, writes 64 B/thread.
__global__ __launch_bounds__(256) void to_grouped(
    const float* __restrict__ in, unsigned short* __restrict__ gout)
{
    int idx = blockIdx.x * 256 + threadIdx.x;   // 4*8*40000 = 1,280,000 exact
    int p  = idx % PLANE;
    int bg = idx / PLANE;                       // b*8+g ; c_base = 32*bg
    const float* src = in + (size_t)bg * GSZ * PLANE + p;

    unsigned short tmp[GSZ];
    #pragma unroll
    for (int j = 0; j < GSZ; ++j) {
        unsigned u = __float_as_uint(src[(size_t)j * PLANE]);
        tmp[j] = (unsigned short)((u + 0x7FFFu + ((u >> 16) & 1u)) >> 16); // RNE
    }
    uint4* dst = (uint4*)(gout + (size_t)idx * GSZ);
    #pragma unroll
    for (int k = 0; k < 4; ++k) {
        uint4 q;
        __builtin_memcpy(&q, &tmp[k * 8], 16);
        dst[k] = q;
    }
}

// ---------- pass 2: gather ----------
__device__ __forceinline__ void fma8(float* acc, const unsigned short* p, float w)
{
    uint4 q = *(const uint4*)p;                 // 8 bf16
    unsigned short u[8];
    __builtin_memcpy(u, &q, 16);
    #pragma unroll
    for (int j = 0; j < 8; ++j)
        acc[j] = fmaf(w, __uint_as_float((unsigned)u[j] << 16), acc[j]);
}

__global__ __launch_bounds__(256) void roi_align_grouped(
    const unsigned short* __restrict__ gfeat,
    const float* __restrict__ rois,
    float* __restrict__ out)
{
    // XCD swizzle: consecutive virtual blocks on one XCD; with g outermost
    // each XCD mostly serves one channel-group (10 MB working set).
    int nb  = gridDim.x;                         // 6272, divisible by 8
    int vb  = (blockIdx.x & 7) * (nb >> 3) + (blockIdx.x >> 3);
    int idx = vb * 256 + threadIdx.x;            // 8*1024*49*4 exact

    int s   = idx & 3;                           // 8-channel slice
    int bin = (idx >> 2) % PP;
    int n   = (idx / (4 * PP)) % N_ROIS;
    int g   = idx / (4 * PP * N_ROIS);
    int ph = bin / 7, pw = bin % 7;

    const float* roi = rois + n * 5;
    int   b  = (int)roi[0];
    float x1 = roi[1] * 0.25f - 0.5f;
    float y1 = roi[2] * 0.25f - 0.5f;
    float x2 = roi[3] * 0.25f - 0.5f;
    float y2 = roi[4] * 0.25f - 0.5f;
    float bin_h = (y2 - y1) / 7.0f;
    float bin_w = (x2 - x1) / 7.0f;

    const unsigned short* plane =
        gfeat + (size_t)(b * NG + g) * PLANE * GSZ + s * 8;

    float acc[8] = {0, 0, 0, 0, 0, 0, 0, 0};

    #pragma unroll
    for (int iy = 0; iy < 2; ++iy) {
        float y = y1 + ((float)ph + ((float)iy + 0.5f) * 0.5f) * bin_h;
        if (y < -1.0f || y > (float)FH) continue;
        float yc  = fminf(fmaxf(y, 0.0f), (float)(FH - 1));
        int   y0  = (int)yc;
        int   y1i = min(y0 + 1, FH - 1);
        float ly  = yc - (float)y0;
        float hy  = 1.0f - ly;

        #pragma unroll
        for (int ix = 0; ix < 2; ++ix) {
            float x = x1 + ((float)pw + ((float)ix + 0.5f) * 0.5f) * bin_w;
            if (x < -1.0f || x > (float)FW) continue;
            float xc  = fminf(fmaxf(x, 0.0f), (float)(FW - 1));
            int   x0  = (int)xc;
            int   x1i = min(x0 + 1, FW - 1);
            float lx  = xc - (float)x0;
            float hx  = 1.0f - lx;

            const unsigned short* r0 = plane + (size_t)(y0  * FW) * GSZ;
            const unsigned short* r1 = plane + (size_t)(y1i * FW) * GSZ;
            fma8(acc, r0 + (size_t)x0  * GSZ, hy * hx);
            fma8(acc, r0 + (size_t)x1i * GSZ, hy * lx);
            fma8(acc, r1 + (size_t)x0  * GSZ, ly * hx);
            fma8(acc, r1 + (size_t)x1i * GSZ, ly * lx);
        }
    }

    // out[n][c][bin], c = g*32 + s*8 + j
    float* o = out + ((size_t)n * CCH + g * GSZ + s * 8) * PP + bin;
    #pragma unroll
    for (int j = 0; j < 8; ++j)
        o[j * PP] = acc[j] * 0.25f;
}

// ---------- fallback (R1 kernel) if ws too small ----------
__global__ __launch_bounds__(256) void roi_align_fallback(
    const float* __restrict__ feat, const float* __restrict__ rois,
    float* __restrict__ out, int total)
{
    int nb  = gridDim.x;
    int vid = (blockIdx.x & 7) * (nb >> 3) + (blockIdx.x >> 3);
    int idx = vid * 256 + threadIdx.x;
    if (idx >= total) return;
    int pw = idx % 7;
    int ph = (idx / 7) % 7;
    int n  = (idx / 49) & (N_ROIS - 1);
    int c  = idx / (49 * N_ROIS);

    const float* roi = rois + n * 5;
    int   b  = (int)roi[0];
    float x1 = roi[1] * 0.25f - 0.5f;
    float y1 = roi[2] * 0.25f - 0.5f;
    float x2 = roi[3] * 0.25f - 0.5f;
    float y2 = roi[4] * 0.25f - 0.5f;
    float bin_h = (y2 - y1) / 7.0f;
    float bin_w = (x2 - x1) / 7.0f;
    const float* plane = feat + ((size_t)b * CCH + c) * PLANE;

    float acc = 0.0f;
    #pragma unroll
    for (int iy = 0; iy < 2; ++iy) {
        float y = y1 + ((float)ph + ((float)iy + 0.5f) * 0.5f) * bin_h;
        if (y < -1.0f || y > (float)FH) continue;
        float yc = fminf(fmaxf(y, 0.0f), (float)(FH - 1));
        int y0 = (int)yc, y1i = min(y0 + 1, FH - 1);
        float ly = yc - (float)y0, hy = 1.0f - ly;
        #pragma unroll
        for (int ix = 0; ix < 2; ++ix) {
            float x = x1 + ((float)pw + ((float)ix + 0.5f) * 0.5f) * bin_w;
            if (x < -1.0f || x > (float)FW) continue;
            float xc = fminf(fmaxf(x, 0.0f), (float)(FW - 1));
            int x0 = (int)xc, x1i = min(x0 + 1, FW - 1);
            float lx = xc - (float)x0, hx = 1.0f - lx;
            acc += hy * (hx * plane[y0 * FW + x0] + lx * plane[y0 * FW + x1i])
                 + ly * (hx * plane[y1i * FW + x0] + lx * plane[y1i * FW + x1i]);
        }
    }
    out[((size_t)n * CCH + c) * PP + ph * 7 + pw] = acc * 0.25f;
}

extern "C" void kernel_launch(void* const* d_in, const int* in_sizes, int n_in,
                              void* d_out, int out_size, void* d_ws, size_t ws_size,
                              hipStream_t stream)
{
    const float* feat = (const float*)d_in[0];
    const float* rois = (const float*)d_in[1];
    float* out = (float*)d_out;

    const size_t ws_needed = (size_t)4 * NG * PLANE * GSZ * 2;  // 81.92 MB bf16

    if (ws_size >= ws_needed) {
        unsigned short* gfeat = (unsigned short*)d_ws;
        to_grouped<<<(4 * NG * PLANE) / 256, 256, 0, stream>>>(feat, gfeat);
        int items = NG * N_ROIS * PP * 4;            // 1,605,632
        roi_align_grouped<<<items / 256, 256, 0, stream>>>(gfeat, rois, out);
    } else {
        int total = out_size;
        int grid = (total + 255) / 256;
        roi_align_fallback<<<grid, 256, 0, stream>>>(feat, rois, out, total);
    }
}

// Round 4
// 291.807 us; speedup vs baseline: 1.5225x; 1.0186x over previous
//
#include <hip/hip_runtime.h>
#include <hip/hip_bf16.h>

// RoIAlign (avg, aligned=True).
//   input: (4, 256, 200, 200) fp32, rois: (1024, 5) fp32
//   pooled 7x7, sampling_ratio=2, spatial_scale=0.25
//   out: (1024, 256, 7, 7) fp32
//
// R3: R2's two-pass grouped-bf16 scheme + ROI counting-sort by image index.
// Sorted ROI order + g-outermost XCD swizzle makes each XCD's instantaneous
// gather working set one (g,b) plane-group = 2.56 MB < 4 MB XCD L2.

#define CCH 256
#define FH 200
#define FW 200
#define N_ROIS 1024
#define PP 49          // 7*7 bins
#define NG 8           // channel groups (256/32)
#define GSZ 32         // channels per group
#define PLANE (FH*FW)

// ---------- pass 0: counting-sort ROIs by image index ----------
__global__ __launch_bounds__(1024) void sort_rois(
    const float* __restrict__ rois, int* __restrict__ perm)
{
    __shared__ int cnt[4];
    __shared__ int base[4];
    int t = threadIdx.x;                 // 1024 threads, one block
    if (t < 4) cnt[t] = 0;
    __syncthreads();
    int b = (int)rois[t * 5];
    int pos = atomicAdd(&cnt[b], 1);
    __syncthreads();
    if (t == 0) {
        int s = 0;
        #pragma unroll
        for (int i = 0; i < 4; ++i) { base[i] = s; s += cnt[i]; }
    }
    __syncthreads();
    perm[base[b] + pos] = t;
}

// ---------- pass 1: NCHW fp32 -> grouped bf16 ----------
__global__ __launch_bounds__(256) void to_grouped(
    const float* __restrict__ in, unsigned short* __restrict__ gout)
{
    int idx = blockIdx.x * 256 + threadIdx.x;   // 4*8*40000 = 1,280,000 exact
    int p  = idx % PLANE;
    int bg = idx / PLANE;                       // b*8+g ; c_base = 32*bg
    const float* src = in + (size_t)bg * GSZ * PLANE + p;

    unsigned short tmp[GSZ];
    #pragma unroll
    for (int j = 0; j < GSZ; ++j) {
        unsigned u = __float_as_uint(src[(size_t)j * PLANE]);
        tmp[j] = (unsigned short)((u + 0x7FFFu + ((u >> 16) & 1u)) >> 16); // RNE
    }
    uint4* dst = (uint4*)(gout + (size_t)idx * GSZ);
    #pragma unroll
    for (int k = 0; k < 4; ++k) {
        uint4 q;
        __builtin_memcpy(&q, &tmp[k * 8], 16);
        dst[k] = q;
    }
}

// ---------- pass 2: gather ----------
__device__ __forceinline__ void fma8(float* acc, const unsigned short* p, float w)
{
    uint4 q = *(const uint4*)p;                 // 8 bf16
    unsigned short u[8];
    __builtin_memcpy(u, &q, 16);
    #pragma unroll
    for (int j = 0; j < 8; ++j)
        acc[j] = fmaf(w, __uint_as_float((unsigned)u[j] << 16), acc[j]);
}

__global__ __launch_bounds__(256) void roi_align_grouped(
    const unsigned short* __restrict__ gfeat,
    const float* __restrict__ rois,
    const int* __restrict__ perm,
    float* __restrict__ out)
{
    // XCD swizzle: 6272 blocks / 8 XCDs = 784-block chunks; one g per XCD.
    int nb  = gridDim.x;                         // 6272, divisible by 8
    int vb  = (blockIdx.x & 7) * (nb >> 3) + (blockIdx.x >> 3);
    int idx = vb * 256 + threadIdx.x;            // 8*1024*49*4 exact

    int s      = idx & 3;                        // 8-channel slice
    int bin    = (idx >> 2) % PP;
    int n_slot = (idx / (4 * PP)) % N_ROIS;      // sorted position
    int g      = idx / (4 * PP * N_ROIS);
    int n      = perm[n_slot];                   // original ROI id
    int ph = bin / 7, pw = bin % 7;

    const float* roi = rois + n * 5;
    int   b  = (int)roi[0];
    float x1 = roi[1] * 0.25f - 0.5f;
    float y1 = roi[2] * 0.25f - 0.5f;
    float x2 = roi[3] * 0.25f - 0.5f;
    float y2 = roi[4] * 0.25f - 0.5f;
    float bin_h = (y2 - y1) / 7.0f;
    float bin_w = (x2 - x1) / 7.0f;

    const unsigned short* plane =
        gfeat + (size_t)(b * NG + g) * PLANE * GSZ + s * 8;

    float acc[8] = {0, 0, 0, 0, 0, 0, 0, 0};

    #pragma unroll
    for (int iy = 0; iy < 2; ++iy) {
        float y = y1 + ((float)ph + ((float)iy + 0.5f) * 0.5f) * bin_h;
        if (y < -1.0f || y > (float)FH) continue;
        float yc  = fminf(fmaxf(y, 0.0f), (float)(FH - 1));
        int   y0  = (int)yc;
        int   y1i = min(y0 + 1, FH - 1);
        float ly  = yc - (float)y0;
        float hy  = 1.0f - ly;

        #pragma unroll
        for (int ix = 0; ix < 2; ++ix) {
            float x = x1 + ((float)pw + ((float)ix + 0.5f) * 0.5f) * bin_w;
            if (x < -1.0f || x > (float)FW) continue;
            float xc  = fminf(fmaxf(x, 0.0f), (float)(FW - 1));
            int   x0  = (int)xc;
            int   x1i = min(x0 + 1, FW - 1);
            float lx  = xc - (float)x0;
            float hx  = 1.0f - lx;

            const unsigned short* r0 = plane + (size_t)(y0  * FW) * GSZ;
            const unsigned short* r1 = plane + (size_t)(y1i * FW) * GSZ;
            fma8(acc, r0 + (size_t)x0  * GSZ, hy * hx);
            fma8(acc, r0 + (size_t)x1i * GSZ, hy * lx);
            fma8(acc, r1 + (size_t)x0  * GSZ, ly * hx);
            fma8(acc, r1 + (size_t)x1i * GSZ, ly * lx);
        }
    }

    // out[n][c][bin], c = g*32 + s*8 + j
    float* o = out + ((size_t)n * CCH + g * GSZ + s * 8) * PP + bin;
    #pragma unroll
    for (int j = 0; j < 8; ++j)
        o[j * PP] = acc[j] * 0.25f;
}

// ---------- fallback (R1 kernel) if ws too small ----------
__global__ __launch_bounds__(256) void roi_align_fallback(
    const float* __restrict__ feat, const float* __restrict__ rois,
    float* __restrict__ out, int total)
{
    int nb  = gridDim.x;
    int vid = (blockIdx.x & 7) * (nb >> 3) + (blockIdx.x >> 3);
    int idx = vid * 256 + threadIdx.x;
    if (idx >= total) return;
    int pw = idx % 7;
    int ph = (idx / 7) % 7;
    int n  = (idx / 49) & (N_ROIS - 1);
    int c  = idx / (49 * N_ROIS);

    const float* roi = rois + n * 5;
    int   b  = (int)roi[0];
    float x1 = roi[1] * 0.25f - 0.5f;
    float y1 = roi[2] * 0.25f - 0.5f;
    float x2 = roi[3] * 0.25f - 0.5f;
    float y2 = roi[4] * 0.25f - 0.5f;
    float bin_h = (y2 - y1) / 7.0f;
    float bin_w = (x2 - x1) / 7.0f;
    const float* plane = feat + ((size_t)b * CCH + c) * PLANE;

    float acc = 0.0f;
    #pragma unroll
    for (int iy = 0; iy < 2; ++iy) {
        float y = y1 + ((float)ph + ((float)iy + 0.5f) * 0.5f) * bin_h;
        if (y < -1.0f || y > (float)FH) continue;
        float yc = fminf(fmaxf(y, 0.0f), (float)(FH - 1));
        int y0 = (int)yc, y1i = min(y0 + 1, FH - 1);
        float ly = yc - (float)y0, hy = 1.0f - ly;
        #pragma unroll
        for (int ix = 0; ix < 2; ++ix) {
            float x = x1 + ((float)pw + ((float)ix + 0.5f) * 0.5f) * bin_w;
            if (x < -1.0f || x > (float)FW) continue;
            float xc = fminf(fmaxf(x, 0.0f), (float)(FW - 1));
            int x0 = (int)xc, x1i = min(x0 + 1, FW - 1);
            float lx = xc - (float)x0, hx = 1.0f - lx;
            acc += hy * (hx * plane[y0 * FW + x0] + lx * plane[y0 * FW + x1i])
                 + ly * (hx * plane[y1i * FW + x0] + lx * plane[y1i * FW + x1i]);
        }
    }
    out[((size_t)n * CCH + c) * PP + ph * 7 + pw] = acc * 0.25f;
}

extern "C" void kernel_launch(void* const* d_in, const int* in_sizes, int n_in,
                              void* d_out, int out_size, void* d_ws, size_t ws_size,
                              hipStream_t stream)
{
    const float* feat = (const float*)d_in[0];
    const float* rois = (const float*)d_in[1];
    float* out = (float*)d_out;

    const size_t gfeat_bytes = (size_t)4 * NG * PLANE * GSZ * 2;  // 81.92 MB
    const size_t ws_needed = gfeat_bytes + N_ROIS * sizeof(int);

    if (ws_size >= ws_needed) {
        unsigned short* gfeat = (unsigned short*)d_ws;
        int* perm = (int*)((char*)d_ws + gfeat_bytes);
        sort_rois<<<1, 1024, 0, stream>>>(rois, perm);
        to_grouped<<<(4 * NG * PLANE) / 256, 256, 0, stream>>>(feat, gfeat);
        int items = NG * N_ROIS * PP * 4;            // 1,605,632
        roi_align_grouped<<<items / 256, 256, 0, stream>>>(gfeat, rois, perm, out);
    } else {
        int total = out_size;
        int grid = (total + 255) / 256;
        roi_align_fallback<<<grid, 256, 0, stream>>>(feat, rois, out, total);
    }
}